// Round 11
// baseline (357.441 us; speedup 1.0000x reference)
//
#include <hip/hip_runtime.h>
#include <hip/hip_bf16.h>
#include <stdint.h>

typedef _Float16 half8 __attribute__((ext_vector_type(8)));
typedef _Float16 half4 __attribute__((ext_vector_type(4)));
typedef float    f32x4 __attribute__((ext_vector_type(4)));

#define MFMA16(a, b, c) __builtin_amdgcn_mfma_f32_16x16x32_f16(a, b, c, 0, 0, 0)

// ---------------------------------------------------------------------------
// Generic fp32->fp16 transpose: X [R][C] fp32 -> Y [C][R] fp16, z-batched.
// ---------------------------------------------------------------------------
__global__ __launch_bounds__(256) void transpose_to_f16(
    const float* __restrict__ X, _Float16* __restrict__ Y,
    int R, int C, long inBS, long outBS)
{
    __shared__ float t[32][33];
    const int bz = blockIdx.z;
    X += (long)bz * inBS;
    Y += (long)bz * outBS;
    const int c0 = blockIdx.x * 32, r0 = blockIdx.y * 32;
    const int tx = threadIdx.x & 31, ty = threadIdx.x >> 5;
#pragma unroll
    for (int i = 0; i < 4; ++i)
        t[ty + i * 8][tx] = X[(long)(r0 + ty + i * 8) * C + c0 + tx];
    __syncthreads();
#pragma unroll
    for (int i = 0; i < 4; ++i)
        Y[(long)(c0 + ty + i * 8) * R + r0 + tx] = (_Float16)t[tx][ty + i * 8];
}

// ---------------------------------------------------------------------------
// MFMA GEMM v2 (unchanged from R9/R10-passing). C = A(fp32) @ BT(fp16).
// ---------------------------------------------------------------------------
__global__ __launch_bounds__(256, 2) void gemm_f16_v2(
    const float* __restrict__ A0, const float* __restrict__ A1,
    const _Float16* __restrict__ BT,
    const float* __restrict__ bias0, const float* __restrict__ bias1,
    void* __restrict__ Cout,
    int N, int lda, int ldbt, int ldc,
    long aBS, long bBS, long cBS,
    int c_half, int atomic, int nks, int kchunk)
{
    __shared__ __align__(16) _Float16 As[128][72];
    __shared__ __align__(16) _Float16 Bs[128][72];

    const int nt = blockIdx.x, mt = blockIdx.y;
    const int b = blockIdx.z / nks, ks = blockIdx.z % nks;
    const int kbeg = ks * kchunk;

    const float* A = A1 ? (b ? A1 : A0) : (A0 + (long)b * aBS);
    const _Float16* Bb = BT + (long)b * bBS;

    const int n0 = nt * 128;
    const int m0 = mt * 128;
    const int tid  = threadIdx.x;
    const int wave = tid >> 6, lane = tid & 63;
    const int m16  = lane & 15, quad = lane >> 4;

    f32x4 acc[2][8];
    {
        f32x4 z = {0.f, 0.f, 0.f, 0.f};
#pragma unroll
        for (int i = 0; i < 2; ++i)
#pragma unroll
            for (int j = 0; j < 8; ++j) acc[i][j] = z;
    }

    for (int k0 = kbeg; k0 < kbeg + kchunk; k0 += 64) {
        {
            const int cc = (tid & 15) * 4;
            const int rb = tid >> 4;
            float4 av[8];
#pragma unroll
            for (int p = 0; p < 8; ++p)
                av[p] = *(const float4*)(A + (long)(m0 + rb + p * 16) * lda + k0 + cc);
#pragma unroll
            for (int p = 0; p < 8; ++p) {
                half4 hv;
                hv[0] = (_Float16)av[p].x; hv[1] = (_Float16)av[p].y;
                hv[2] = (_Float16)av[p].z; hv[3] = (_Float16)av[p].w;
                *(half4*)&As[rb + p * 16][cc] = hv;
            }
        }
        {
            const int j  = tid >> 1;
            const int cc = (tid & 1) * 32;
            int jn = n0 + j; if (jn > N - 1) jn = N - 1;
            const _Float16* bp = Bb + (long)jn * ldbt + k0 + cc;
            half8 b0 = *(const half8*)(bp);
            half8 b1 = *(const half8*)(bp + 8);
            half8 b2 = *(const half8*)(bp + 16);
            half8 b3 = *(const half8*)(bp + 24);
            *(half8*)&Bs[j][cc]      = b0;
            *(half8*)&Bs[j][cc + 8]  = b1;
            *(half8*)&Bs[j][cc + 16] = b2;
            *(half8*)&Bs[j][cc + 24] = b3;
        }
        __syncthreads();
#pragma unroll
        for (int kss = 0; kss < 2; ++kss) {
            const int ko = kss * 32 + quad * 8;
            const half8 a0 = *(const half8*)&As[wave * 32 + m16][ko];
            const half8 a1 = *(const half8*)&As[wave * 32 + 16 + m16][ko];
#pragma unroll
            for (int c = 0; c < 8; ++c) {
                const half8 bf = *(const half8*)&Bs[c * 16 + m16][ko];
                acc[0][c] = MFMA16(a0, bf, acc[0][c]);
                acc[1][c] = MFMA16(a1, bf, acc[1][c]);
            }
        }
        __syncthreads();
    }

    const float* bias = b ? bias1 : bias0;
    const int addb = (bias != nullptr) && (kbeg == 0);
#pragma unroll
    for (int hh = 0; hh < 2; ++hh) {
#pragma unroll
        for (int c = 0; c < 8; ++c) {
            const int col = n0 + c * 16 + m16;
            if (col >= N) continue;
            const float bb = addb ? bias[col] : 0.f;
#pragma unroll
            for (int r = 0; r < 4; ++r) {
                const int row = m0 + wave * 32 + hh * 16 + quad * 4 + r;
                const float v = acc[hh][c][r] + bb;
                const long idx = (long)b * cBS + (long)row * ldc + col;
                if (atomic)      atomicAdd(&((float*)Cout)[idx], v);
                else if (c_half) ((_Float16*)Cout)[idx] = (_Float16)v;
                else             ((float*)Cout)[idx] = v;
            }
        }
    }
}

// ---------------------------------------------------------------------------
// Pass 1: per (b,h,s) row stats (unchanged from R10-passing).
// ---------------------------------------------------------------------------
__global__ __launch_bounds__(256, 2) void attn_stats(
    const _Float16* __restrict__ q_all, const _Float16* __restrict__ k_all,
    float* __restrict__ m_out, float* __restrict__ il_out)
{
    const int st = blockIdx.x, h = blockIdx.y, b = blockIdx.z;
    const int tid = threadIdx.x, wave = tid >> 6, lane = tid & 63;
    const int m16 = lane & 15, quad = lane >> 4;
    const int s0 = st * 64 + wave * 16;

    const _Float16* qp = q_all + ((long)(b * 1024 + s0 + m16)) * 1024 + h * 64 + quad * 8;
    const half8 a0 = *(const half8*)qp;
    const half8 a1 = *(const half8*)(qp + 32);

    float mr[4], lr[4];
#pragma unroll
    for (int r = 0; r < 4; ++r) { mr[r] = -3.0e38f; lr[r] = 0.f; }

    const _Float16* kb = k_all + ((long)(b * 1024 + m16)) * 1024 + h * 64 + quad * 8;
    const int ngroups = st + 1;

    half8 cur[4][2], nxt[4][2];
#pragma unroll
    for (int t = 0; t < 4; ++t) {
        const _Float16* kp = kb + (long)(t * 16) * 1024;
        cur[t][0] = *(const half8*)kp;
        cur[t][1] = *(const half8*)(kp + 32);
    }

    for (int g = 0; g < ngroups; ++g) {
        if (g + 1 < ngroups) {
#pragma unroll
            for (int t = 0; t < 4; ++t) {
                const _Float16* kp = kb + (long)((g + 1) * 64 + t * 16) * 1024;
                nxt[t][0] = *(const half8*)kp;
                nxt[t][1] = *(const half8*)(kp + 32);
            }
        }
        if (g < st) {
#pragma unroll
            for (int t = 0; t < 4; ++t) {
                f32x4 c = {0.f, 0.f, 0.f, 0.f};
                c = MFMA16(a0, cur[t][0], c);
                c = MFMA16(a1, cur[t][1], c);
#pragma unroll
                for (int r = 0; r < 4; ++r) {
                    const float z  = c[r] * 0.125f;
                    const float nm = fmaxf(mr[r], z);
                    lr[r] = lr[r] * __expf(mr[r] - nm) + __expf(z - nm);
                    mr[r] = nm;
                }
            }
        } else {
#pragma unroll
            for (int t = 0; t < 4; ++t) {
                f32x4 c = {0.f, 0.f, 0.f, 0.f};
                c = MFMA16(a0, cur[t][0], c);
                c = MFMA16(a1, cur[t][1], c);
                const int col = g * 64 + t * 16 + m16;
#pragma unroll
                for (int r = 0; r < 4; ++r) {
                    const int row = s0 + quad * 4 + r;
                    if (col <= row) {
                        const float z  = c[r] * 0.125f;
                        const float nm = fmaxf(mr[r], z);
                        lr[r] = lr[r] * __expf(mr[r] - nm) + __expf(z - nm);
                        mr[r] = nm;
                    }
                }
            }
        }
#pragma unroll
        for (int t = 0; t < 4; ++t) { cur[t][0] = nxt[t][0]; cur[t][1] = nxt[t][1]; }
    }

#pragma unroll
    for (int mk = 1; mk < 16; mk <<= 1) {
#pragma unroll
        for (int r = 0; r < 4; ++r) {
            const float om = __shfl_xor(mr[r], mk);
            const float ol = __shfl_xor(lr[r], mk);
            const float nm = fmaxf(mr[r], om);
            lr[r] = lr[r] * __expf(mr[r] - nm) + ol * __expf(om - nm);
            mr[r] = nm;
        }
    }
    if (m16 == 0) {
#pragma unroll
        for (int r = 0; r < 4; ++r) {
            const long idx = ((long)(b * 16 + h)) * 1024 + s0 + quad * 4 + r;
            m_out[idx]  = mr[r];
            il_out[idx] = 1.f / lr[r];
        }
    }
}

// ---------------------------------------------------------------------------
// Pass 2 v3: attn_mean = (1/H) sum_h softmax, heads SPLIT 2-WAY ACROSS GRID.
// R10 evidence: register-prefetch pipeline was defeated by the compiler
// (VGPR 52 << buffer size; dur unchanged) — the limiter is TLP (18% occ,
// 2.1 full-work blocks/CU). z = b*2+hh doubles resident waves; each block
// does 8 heads and atomicAdds its partial into pre-zeroed attn (2 atomics
// per element — negligible contention). Upper-triangle blocks exit (memset
// supplies the zeros). m/il vectorized to float4.
// ---------------------------------------------------------------------------
__global__ __launch_bounds__(256, 2) void attn_pmean(
    const _Float16* __restrict__ q_all, const _Float16* __restrict__ k_all,
    const float* __restrict__ m_in, const float* __restrict__ il_in,
    float* __restrict__ attn)
{
    const int ttile = blockIdx.x, stile = blockIdx.y;
    if (ttile > stile) return;
    const int b = blockIdx.z >> 1, hh = blockIdx.z & 1;
    const int tid = threadIdx.x;
    const int wave = tid >> 6, lane = tid & 63;
    const int m16 = lane & 15, quad = lane >> 4;
    const int s0 = stile * 64 + wave * 16;
    const int t0 = ttile * 64;
    const int diag = (ttile == stile);

    const _Float16* qbase = q_all + ((long)(b * 1024 + s0 + m16)) * 1024 + quad * 8;
    const _Float16* kbase = k_all + ((long)(b * 1024 + t0 + m16)) * 1024 + quad * 8;
    const long sbase = ((long)(b * 16)) * 1024 + s0 + quad * 4;

    float pm[4][4];
#pragma unroll
    for (int c = 0; c < 4; ++c)
#pragma unroll
        for (int r = 0; r < 4; ++r) pm[c][r] = 0.f;

    for (int h = hh * 8; h < hh * 8 + 8; ++h) {
        const int ho = h * 64;
        const half8 qa0 = *(const half8*)(qbase + ho);
        const half8 qa1 = *(const half8*)(qbase + ho + 32);
        half8 kf[4][2];
#pragma unroll
        for (int c = 0; c < 4; ++c) {
            const _Float16* kp = kbase + (long)(c * 16) * 1024 + ho;
            kf[c][0] = *(const half8*)kp;
            kf[c][1] = *(const half8*)(kp + 32);
        }
        const long idx = sbase + (long)h * 1024;
        const float4 mv = *(const float4*)&m_in[idx];
        const float4 iv = *(const float4*)&il_in[idx];
        const float mrow[4] = {mv.x, mv.y, mv.z, mv.w};
        const float irow[4] = {iv.x, iv.y, iv.z, iv.w};

        if (!diag) {
#pragma unroll
            for (int c = 0; c < 4; ++c) {
                f32x4 cc = {0.f, 0.f, 0.f, 0.f};
                cc = MFMA16(qa0, kf[c][0], cc);
                cc = MFMA16(qa1, kf[c][1], cc);
#pragma unroll
                for (int r = 0; r < 4; ++r)
                    pm[c][r] += __expf(cc[r] * 0.125f - mrow[r]) * irow[r];
            }
        } else {
#pragma unroll
            for (int c = 0; c < 4; ++c) {
                f32x4 cc = {0.f, 0.f, 0.f, 0.f};
                cc = MFMA16(qa0, kf[c][0], cc);
                cc = MFMA16(qa1, kf[c][1], cc);
                const int col = t0 + c * 16 + m16;
#pragma unroll
                for (int r = 0; r < 4; ++r) {
                    const int row = s0 + quad * 4 + r;
                    if (col <= row)
                        pm[c][r] += __expf(cc[r] * 0.125f - mrow[r]) * irow[r];
                }
            }
        }
    }

#pragma unroll
    for (int c = 0; c < 4; ++c) {
#pragma unroll
        for (int r = 0; r < 4; ++r) {
            const int row = s0 + quad * 4 + r;
            const int col = t0 + c * 16 + m16;
            atomicAdd(&attn[((long)(b * 1024 + row)) * 1024 + col], pm[c][r] * 0.0625f);
        }
    }
}

// ---------------------------------------------------------------------------
extern "C" void kernel_launch(void* const* d_in, const int* in_sizes, int n_in,
                              void* d_out, int out_size, void* d_ws, size_t ws_size,
                              hipStream_t stream)
{
    const float* queries = (const float*)d_in[0];
    const float* keys    = (const float*)d_in[1];
    const float* values  = (const float*)d_in[2];
    const float* Wq = (const float*)d_in[4];
    const float* bq = (const float*)d_in[5];
    const float* Wk = (const float*)d_in[6];
    const float* bk = (const float*)d_in[7];
    const float* Wv = (const float*)d_in[8];
    const float* bv = (const float*)d_in[9];
    const float* Wo = (const float*)d_in[10];
    const float* bo = (const float*)d_in[11];

    float* out_ptr  = (float*)d_out;                   // [4096][1024]
    float* attn_ptr = out_ptr + (long)4096 * 1024;     // [4][1024][1024]

    uint8_t* w = (uint8_t*)d_ws;
    size_t off = 0;
    auto alloc = [&](size_t bytes) {
        void* p = w + off;
        off = (off + bytes + 255) & ~(size_t)255;
        return p;
    };
    _Float16* WqkT  = (_Float16*)alloc((size_t)2 * 1024 * 1024 * 2); // WqT|WkT [n][d]
    _Float16* WvT   = (_Float16*)alloc((size_t)64 * 1024 * 2);       // [e][d]
    _Float16* WoT   = (_Float16*)alloc((size_t)1024 * 64 * 2);       // [d][e]
    _Float16* qkall = (_Float16*)alloc((size_t)2 * 4194304 * 2);     // qall|kall
    float*    vbuf  = (float*)alloc((size_t)4096 * 64 * 4);
    _Float16* vT    = (_Float16*)alloc((size_t)4 * 64 * 1024 * 2);   // per-b [e][t]
    float*    ctx   = (float*)alloc((size_t)4096 * 64 * 4);
    float*    mbuf  = (float*)alloc((size_t)65536 * 4);
    float*    ilbuf = (float*)alloc((size_t)65536 * 4);
    (void)ws_size; (void)in_sizes; (void)n_in; (void)out_size;

    _Float16* qall = qkall;
    _Float16* kall = qkall + (long)4194304;

    // weight transposes/conversions
    transpose_to_f16<<<dim3(2, 32, 16), 256, 0, stream>>>(Wq, WqkT, 1024, 64, 65536, 65536);
    transpose_to_f16<<<dim3(2, 32, 16), 256, 0, stream>>>(Wk, WqkT + (long)1024 * 1024, 1024, 64, 65536, 65536);
    transpose_to_f16<<<dim3(2, 32, 1),  256, 0, stream>>>(Wv, WvT, 1024, 64, 0, 0);
    transpose_to_f16<<<dim3(32, 2, 1),  256, 0, stream>>>(Wo, WoT, 64, 1024, 0, 0);

    // fused q+k projection: z selects queries/Wq/bq vs keys/Wk/bk; 512 blocks
    gemm_f16_v2<<<dim3(8, 32, 2), 256, 0, stream>>>(
        queries, keys, WqkT, bq, bk, qkall,
        1024, 1024, 1024, 1024,
        0, (long)1048576, (long)4194304,
        /*c_half=*/1, /*atomic=*/0, /*nks=*/1, /*kchunk=*/1024);

    // v projection: split-K x8 atomic into vbuf (zeroed) -> 256 blocks
    hipMemsetAsync(vbuf, 0, (size_t)4096 * 64 * 4, stream);
    gemm_f16_v2<<<dim3(1, 32, 8), 256, 0, stream>>>(
        values, nullptr, WvT, bv, nullptr, vbuf,
        64, 1024, 1024, 64,
        0, 0, 0,
        /*c_half=*/0, /*atomic=*/1, /*nks=*/8, /*kchunk=*/128);

    // vT per batch: [1024][64] -> [64][1024] fp16
    transpose_to_f16<<<dim3(2, 32, 4), 256, 0, stream>>>(vbuf, vT, 1024, 64, 65536, 65536);

    // softmax stats, then zero attn, then head-split head-averaged probs
    attn_stats<<<dim3(16, 16, 4), 256, 0, stream>>>(qall, kall, mbuf, ilbuf);
    hipMemsetAsync(attn_ptr, 0, (size_t)4 * 1024 * 1024 * 4, stream);
    attn_pmean<<<dim3(16, 16, 8), 256, 0, stream>>>(qall, kall, mbuf, ilbuf, attn_ptr);

    // ctx[b] = attn_mean[b] @ v[b]: batch x split-K x8 atomic -> 256 blocks
    hipMemsetAsync(ctx, 0, (size_t)4096 * 64 * 4, stream);
    gemm_f16_v2<<<dim3(1, 8, 32), 256, 0, stream>>>(
        attn_ptr, nullptr, vT, nullptr, nullptr, ctx,
        64, 1024, 1024, 64,
        (long)1048576, (long)65536, (long)65536,
        /*c_half=*/0, /*atomic=*/1, /*nks=*/8, /*kchunk=*/128);

    // out = ctx @ Wo + bo (K=64: single iteration)
    gemm_f16_v2<<<dim3(8, 32, 1), 256, 0, stream>>>(
        ctx, nullptr, WoT, bo, nullptr, out_ptr,
        1024, 64, 64, 1024,
        0, 0, 0,
        /*c_half=*/0, /*atomic=*/0, /*nks=*/1, /*kchunk=*/64);
}

// Round 12
// 297.821 us; speedup vs baseline: 1.2002x; 1.2002x over previous
//
#include <hip/hip_runtime.h>
#include <hip/hip_bf16.h>
#include <stdint.h>

typedef _Float16 half8 __attribute__((ext_vector_type(8)));
typedef _Float16 half4 __attribute__((ext_vector_type(4)));
typedef float    f32x4 __attribute__((ext_vector_type(4)));

#define MFMA16(a, b, c) __builtin_amdgcn_mfma_f32_16x16x32_f16(a, b, c, 0, 0, 0)

// ---------------------------------------------------------------------------
// Generic fp32->fp16 transpose: X [R][C] fp32 -> Y [C][R] fp16, z-batched.
// ---------------------------------------------------------------------------
__global__ __launch_bounds__(256) void transpose_to_f16(
    const float* __restrict__ X, _Float16* __restrict__ Y,
    int R, int C, long inBS, long outBS)
{
    __shared__ float t[32][33];
    const int bz = blockIdx.z;
    X += (long)bz * inBS;
    Y += (long)bz * outBS;
    const int c0 = blockIdx.x * 32, r0 = blockIdx.y * 32;
    const int tx = threadIdx.x & 31, ty = threadIdx.x >> 5;
#pragma unroll
    for (int i = 0; i < 4; ++i)
        t[ty + i * 8][tx] = X[(long)(r0 + ty + i * 8) * C + c0 + tx];
    __syncthreads();
#pragma unroll
    for (int i = 0; i < 4; ++i)
        Y[(long)(c0 + ty + i * 8) * R + r0 + tx] = (_Float16)t[tx][ty + i * 8];
}

// ---------------------------------------------------------------------------
// MFMA GEMM v2 (unchanged from R9-R11 passing). C = A(fp32) @ BT(fp16).
// ---------------------------------------------------------------------------
__global__ __launch_bounds__(256, 2) void gemm_f16_v2(
    const float* __restrict__ A0, const float* __restrict__ A1,
    const _Float16* __restrict__ BT,
    const float* __restrict__ bias0, const float* __restrict__ bias1,
    void* __restrict__ Cout,
    int N, int lda, int ldbt, int ldc,
    long aBS, long bBS, long cBS,
    int c_half, int atomic, int nks, int kchunk)
{
    __shared__ __align__(16) _Float16 As[128][72];
    __shared__ __align__(16) _Float16 Bs[128][72];

    const int nt = blockIdx.x, mt = blockIdx.y;
    const int b = blockIdx.z / nks, ks = blockIdx.z % nks;
    const int kbeg = ks * kchunk;

    const float* A = A1 ? (b ? A1 : A0) : (A0 + (long)b * aBS);
    const _Float16* Bb = BT + (long)b * bBS;

    const int n0 = nt * 128;
    const int m0 = mt * 128;
    const int tid  = threadIdx.x;
    const int wave = tid >> 6, lane = tid & 63;
    const int m16  = lane & 15, quad = lane >> 4;

    f32x4 acc[2][8];
    {
        f32x4 z = {0.f, 0.f, 0.f, 0.f};
#pragma unroll
        for (int i = 0; i < 2; ++i)
#pragma unroll
            for (int j = 0; j < 8; ++j) acc[i][j] = z;
    }

    for (int k0 = kbeg; k0 < kbeg + kchunk; k0 += 64) {
        {
            const int cc = (tid & 15) * 4;
            const int rb = tid >> 4;
            float4 av[8];
#pragma unroll
            for (int p = 0; p < 8; ++p)
                av[p] = *(const float4*)(A + (long)(m0 + rb + p * 16) * lda + k0 + cc);
#pragma unroll
            for (int p = 0; p < 8; ++p) {
                half4 hv;
                hv[0] = (_Float16)av[p].x; hv[1] = (_Float16)av[p].y;
                hv[2] = (_Float16)av[p].z; hv[3] = (_Float16)av[p].w;
                *(half4*)&As[rb + p * 16][cc] = hv;
            }
        }
        {
            const int j  = tid >> 1;
            const int cc = (tid & 1) * 32;
            int jn = n0 + j; if (jn > N - 1) jn = N - 1;
            const _Float16* bp = Bb + (long)jn * ldbt + k0 + cc;
            half8 b0 = *(const half8*)(bp);
            half8 b1 = *(const half8*)(bp + 8);
            half8 b2 = *(const half8*)(bp + 16);
            half8 b3 = *(const half8*)(bp + 24);
            *(half8*)&Bs[j][cc]      = b0;
            *(half8*)&Bs[j][cc + 8]  = b1;
            *(half8*)&Bs[j][cc + 16] = b2;
            *(half8*)&Bs[j][cc + 24] = b3;
        }
        __syncthreads();
#pragma unroll
        for (int kss = 0; kss < 2; ++kss) {
            const int ko = kss * 32 + quad * 8;
            const half8 a0 = *(const half8*)&As[wave * 32 + m16][ko];
            const half8 a1 = *(const half8*)&As[wave * 32 + 16 + m16][ko];
#pragma unroll
            for (int c = 0; c < 8; ++c) {
                const half8 bf = *(const half8*)&Bs[c * 16 + m16][ko];
                acc[0][c] = MFMA16(a0, bf, acc[0][c]);
                acc[1][c] = MFMA16(a1, bf, acc[1][c]);
            }
        }
        __syncthreads();
    }

    const float* bias = b ? bias1 : bias0;
    const int addb = (bias != nullptr) && (kbeg == 0);
#pragma unroll
    for (int hh = 0; hh < 2; ++hh) {
#pragma unroll
        for (int c = 0; c < 8; ++c) {
            const int col = n0 + c * 16 + m16;
            if (col >= N) continue;
            const float bb = addb ? bias[col] : 0.f;
#pragma unroll
            for (int r = 0; r < 4; ++r) {
                const int row = m0 + wave * 32 + hh * 16 + quad * 4 + r;
                const float v = acc[hh][c][r] + bb;
                const long idx = (long)b * cBS + (long)row * ldc + col;
                if (atomic)      atomicAdd(&((float*)Cout)[idx], v);
                else if (c_half) ((_Float16*)Cout)[idx] = (_Float16)v;
                else             ((float*)Cout)[idx] = v;
            }
        }
    }
}

// ---------------------------------------------------------------------------
// Pass 1: per (b,h,s) row stats (unchanged from R10/R11-passing).
// ---------------------------------------------------------------------------
__global__ __launch_bounds__(256, 2) void attn_stats(
    const _Float16* __restrict__ q_all, const _Float16* __restrict__ k_all,
    float* __restrict__ m_out, float* __restrict__ il_out)
{
    const int st = blockIdx.x, h = blockIdx.y, b = blockIdx.z;
    const int tid = threadIdx.x, wave = tid >> 6, lane = tid & 63;
    const int m16 = lane & 15, quad = lane >> 4;
    const int s0 = st * 64 + wave * 16;

    const _Float16* qp = q_all + ((long)(b * 1024 + s0 + m16)) * 1024 + h * 64 + quad * 8;
    const half8 a0 = *(const half8*)qp;
    const half8 a1 = *(const half8*)(qp + 32);

    float mr[4], lr[4];
#pragma unroll
    for (int r = 0; r < 4; ++r) { mr[r] = -3.0e38f; lr[r] = 0.f; }

    const _Float16* kb = k_all + ((long)(b * 1024 + m16)) * 1024 + h * 64 + quad * 8;
    const int ngroups = st + 1;

    half8 cur[4][2], nxt[4][2];
#pragma unroll
    for (int t = 0; t < 4; ++t) {
        const _Float16* kp = kb + (long)(t * 16) * 1024;
        cur[t][0] = *(const half8*)kp;
        cur[t][1] = *(const half8*)(kp + 32);
    }

    for (int g = 0; g < ngroups; ++g) {
        if (g + 1 < ngroups) {
#pragma unroll
            for (int t = 0; t < 4; ++t) {
                const _Float16* kp = kb + (long)((g + 1) * 64 + t * 16) * 1024;
                nxt[t][0] = *(const half8*)kp;
                nxt[t][1] = *(const half8*)(kp + 32);
            }
        }
        if (g < st) {
#pragma unroll
            for (int t = 0; t < 4; ++t) {
                f32x4 c = {0.f, 0.f, 0.f, 0.f};
                c = MFMA16(a0, cur[t][0], c);
                c = MFMA16(a1, cur[t][1], c);
#pragma unroll
                for (int r = 0; r < 4; ++r) {
                    const float z  = c[r] * 0.125f;
                    const float nm = fmaxf(mr[r], z);
                    lr[r] = lr[r] * __expf(mr[r] - nm) + __expf(z - nm);
                    mr[r] = nm;
                }
            }
        } else {
#pragma unroll
            for (int t = 0; t < 4; ++t) {
                f32x4 c = {0.f, 0.f, 0.f, 0.f};
                c = MFMA16(a0, cur[t][0], c);
                c = MFMA16(a1, cur[t][1], c);
                const int col = g * 64 + t * 16 + m16;
#pragma unroll
                for (int r = 0; r < 4; ++r) {
                    const int row = s0 + quad * 4 + r;
                    if (col <= row) {
                        const float z  = c[r] * 0.125f;
                        const float nm = fmaxf(mr[r], z);
                        lr[r] = lr[r] * __expf(mr[r] - nm) + __expf(z - nm);
                        mr[r] = nm;
                    }
                }
            }
        }
#pragma unroll
        for (int t = 0; t < 4; ++t) { cur[t][0] = nxt[t][0]; cur[t][1] = nxt[t][1]; }
    }

#pragma unroll
    for (int mk = 1; mk < 16; mk <<= 1) {
#pragma unroll
        for (int r = 0; r < 4; ++r) {
            const float om = __shfl_xor(mr[r], mk);
            const float ol = __shfl_xor(lr[r], mk);
            const float nm = fmaxf(mr[r], om);
            lr[r] = lr[r] * __expf(mr[r] - nm) + ol * __expf(om - nm);
            mr[r] = nm;
        }
    }
    if (m16 == 0) {
#pragma unroll
        for (int r = 0; r < 4; ++r) {
            const long idx = ((long)(b * 16 + h)) * 1024 + s0 + quad * 4 + r;
            m_out[idx]  = mr[r];
            il_out[idx] = 1.f / lr[r];
        }
    }
}

// ---------------------------------------------------------------------------
// Pass 2 v4: attn_mean = (1/H) sum_h softmax — LDS-STAGED like the GEMM.
// R10/R11 evidence: per-wave scattered global reads (16 txns/instr, 4x
// redundant across waves, FETCH 2x unique data) made pmean latency-bound at
// ~615 GB/s with all pipes idle; neither register pipelining nor more
// blocks helped. Now each head stages the 64x64 q- and k-tiles into padded
// LDS with coalesced batched loads (one vmcnt drain/head, overlapped with
// previous head's compute), and all 4 waves share them via conflict-free
// ds_read_b128 (stride 72 halves -> 2-way, free per m136). Direct stores,
// no atomics; upper-triangle tiles zero-fill inline.
// ---------------------------------------------------------------------------
__global__ __launch_bounds__(256, 2) void attn_pmean(
    const _Float16* __restrict__ q_all, const _Float16* __restrict__ k_all,
    const float* __restrict__ m_in, const float* __restrict__ il_in,
    float* __restrict__ attn)
{
    const int ttile = blockIdx.x, stile = blockIdx.y, b = blockIdx.z;
    const int tid = threadIdx.x;
    if (ttile > stile) {
        const int c4 = (tid & 15) * 4;
        float4 z = {0.f, 0.f, 0.f, 0.f};
#pragma unroll
        for (int i = 0; i < 4; ++i) {
            const int r = stile * 64 + (tid >> 4) + i * 16;
            *(float4*)&attn[((long)(b * 1024 + r)) * 1024 + ttile * 64 + c4] = z;
        }
        return;
    }

    __shared__ __align__(16) _Float16 qs[64][72];
    __shared__ __align__(16) _Float16 ks[64][72];

    const int wave = tid >> 6, lane = tid & 63;
    const int m16 = lane & 15, quad = lane >> 4;
    const int s0 = stile * 64;
    const int t0 = ttile * 64;
    const int sw = s0 + wave * 16;          // wave's q-row base
    const int diag = (ttile == stile);

    // staging role: thread -> (row, 32B chunk)
    const int srow = tid >> 2;              // 0..63
    const int scol = (tid & 3) * 16;        // halves: 0,16,32,48

    const _Float16* qsrc = q_all + ((long)(b * 1024 + s0 + srow)) * 1024 + scol;
    const _Float16* ksrc = k_all + ((long)(b * 1024 + t0 + srow)) * 1024 + scol;
    const long sbase = ((long)(b * 16)) * 1024 + sw + quad * 4;

    float pm[4][4];
#pragma unroll
    for (int c = 0; c < 4; ++c)
#pragma unroll
        for (int r = 0; r < 4; ++r) pm[c][r] = 0.f;

    for (int h = 0; h < 16; ++h) {
        const int ho = h * 64;
        // batched global loads (issue before barrier; latency overlaps
        // the previous head's compute + barrier)
        const half8 q0 = *(const half8*)(qsrc + ho);
        const half8 q1 = *(const half8*)(qsrc + ho + 8);
        const half8 k0 = *(const half8*)(ksrc + ho);
        const half8 k1 = *(const half8*)(ksrc + ho + 8);
        const long idx = sbase + (long)h * 1024;
        const float4 mv = *(const float4*)&m_in[idx];
        const float4 iv = *(const float4*)&il_in[idx];

        __syncthreads();   // all waves done reading LDS for head h-1
        *(half8*)&qs[srow][scol]     = q0;
        *(half8*)&qs[srow][scol + 8] = q1;
        *(half8*)&ks[srow][scol]     = k0;
        *(half8*)&ks[srow][scol + 8] = k1;
        __syncthreads();   // tiles visible

        const half8 a0 = *(const half8*)&qs[wave * 16 + m16][quad * 8];
        const half8 a1 = *(const half8*)&qs[wave * 16 + m16][quad * 8 + 32];
        const float mrow[4] = {mv.x, mv.y, mv.z, mv.w};
        const float irow[4] = {iv.x, iv.y, iv.z, iv.w};

        if (!diag) {
#pragma unroll
            for (int c = 0; c < 4; ++c) {
                const half8 b0 = *(const half8*)&ks[c * 16 + m16][quad * 8];
                const half8 b1 = *(const half8*)&ks[c * 16 + m16][quad * 8 + 32];
                f32x4 cc = {0.f, 0.f, 0.f, 0.f};
                cc = MFMA16(a0, b0, cc);
                cc = MFMA16(a1, b1, cc);
#pragma unroll
                for (int r = 0; r < 4; ++r)
                    pm[c][r] += __expf(cc[r] * 0.125f - mrow[r]) * irow[r];
            }
        } else {
#pragma unroll
            for (int c = 0; c < 4; ++c) {
                const half8 b0 = *(const half8*)&ks[c * 16 + m16][quad * 8];
                const half8 b1 = *(const half8*)&ks[c * 16 + m16][quad * 8 + 32];
                f32x4 cc = {0.f, 0.f, 0.f, 0.f};
                cc = MFMA16(a0, b0, cc);
                cc = MFMA16(a1, b1, cc);
                const int col = t0 + c * 16 + m16;
#pragma unroll
                for (int r = 0; r < 4; ++r) {
                    const int row = sw + quad * 4 + r;
                    if (col <= row)
                        pm[c][r] += __expf(cc[r] * 0.125f - mrow[r]) * irow[r];
                }
            }
        }
    }

#pragma unroll
    for (int c = 0; c < 4; ++c) {
#pragma unroll
        for (int r = 0; r < 4; ++r) {
            const int row = sw + quad * 4 + r;
            const int col = t0 + c * 16 + m16;
            attn[((long)(b * 1024 + row)) * 1024 + col] = pm[c][r] * 0.0625f;
        }
    }
}

// ---------------------------------------------------------------------------
extern "C" void kernel_launch(void* const* d_in, const int* in_sizes, int n_in,
                              void* d_out, int out_size, void* d_ws, size_t ws_size,
                              hipStream_t stream)
{
    const float* queries = (const float*)d_in[0];
    const float* keys    = (const float*)d_in[1];
    const float* values  = (const float*)d_in[2];
    const float* Wq = (const float*)d_in[4];
    const float* bq = (const float*)d_in[5];
    const float* Wk = (const float*)d_in[6];
    const float* bk = (const float*)d_in[7];
    const float* Wv = (const float*)d_in[8];
    const float* bv = (const float*)d_in[9];
    const float* Wo = (const float*)d_in[10];
    const float* bo = (const float*)d_in[11];

    float* out_ptr  = (float*)d_out;                   // [4096][1024]
    float* attn_ptr = out_ptr + (long)4096 * 1024;     // [4][1024][1024]

    uint8_t* w = (uint8_t*)d_ws;
    size_t off = 0;
    auto alloc = [&](size_t bytes) {
        void* p = w + off;
        off = (off + bytes + 255) & ~(size_t)255;
        return p;
    };
    _Float16* WqkT  = (_Float16*)alloc((size_t)2 * 1024 * 1024 * 2); // WqT|WkT [n][d]
    _Float16* WvT   = (_Float16*)alloc((size_t)64 * 1024 * 2);       // [e][d]
    _Float16* WoT   = (_Float16*)alloc((size_t)1024 * 64 * 2);       // [d][e]
    _Float16* qkall = (_Float16*)alloc((size_t)2 * 4194304 * 2);     // qall|kall
    float*    vbuf  = (float*)alloc((size_t)4096 * 64 * 4);
    _Float16* vT    = (_Float16*)alloc((size_t)4 * 64 * 1024 * 2);   // per-b [e][t]
    float*    ctx   = (float*)alloc((size_t)4096 * 64 * 4);
    float*    mbuf  = (float*)alloc((size_t)65536 * 4);
    float*    ilbuf = (float*)alloc((size_t)65536 * 4);
    (void)ws_size; (void)in_sizes; (void)n_in; (void)out_size;

    _Float16* qall = qkall;
    _Float16* kall = qkall + (long)4194304;

    // weight transposes/conversions
    transpose_to_f16<<<dim3(2, 32, 16), 256, 0, stream>>>(Wq, WqkT, 1024, 64, 65536, 65536);
    transpose_to_f16<<<dim3(2, 32, 16), 256, 0, stream>>>(Wk, WqkT + (long)1024 * 1024, 1024, 64, 65536, 65536);
    transpose_to_f16<<<dim3(2, 32, 1),  256, 0, stream>>>(Wv, WvT, 1024, 64, 0, 0);
    transpose_to_f16<<<dim3(32, 2, 1),  256, 0, stream>>>(Wo, WoT, 64, 1024, 0, 0);

    // fused q+k projection: z selects queries/Wq/bq vs keys/Wk/bk; 512 blocks
    gemm_f16_v2<<<dim3(8, 32, 2), 256, 0, stream>>>(
        queries, keys, WqkT, bq, bk, qkall,
        1024, 1024, 1024, 1024,
        0, (long)1048576, (long)4194304,
        /*c_half=*/1, /*atomic=*/0, /*nks=*/1, /*kchunk=*/1024);

    // v projection: split-K x8 atomic into vbuf (zeroed) -> 256 blocks
    hipMemsetAsync(vbuf, 0, (size_t)4096 * 64 * 4, stream);
    gemm_f16_v2<<<dim3(1, 32, 8), 256, 0, stream>>>(
        values, nullptr, WvT, bv, nullptr, vbuf,
        64, 1024, 1024, 64,
        0, 0, 0,
        /*c_half=*/0, /*atomic=*/1, /*nks=*/8, /*kchunk=*/128);

    // vT per batch: [1024][64] -> [64][1024] fp16
    transpose_to_f16<<<dim3(2, 32, 4), 256, 0, stream>>>(vbuf, vT, 1024, 64, 65536, 65536);

    // softmax stats then LDS-staged head-averaged probabilities
    attn_stats<<<dim3(16, 16, 4), 256, 0, stream>>>(qall, kall, mbuf, ilbuf);
    attn_pmean<<<dim3(16, 16, 4), 256, 0, stream>>>(qall, kall, mbuf, ilbuf, attn_ptr);

    // ctx[b] = attn_mean[b] @ v[b]: batch x split-K x8 atomic -> 256 blocks
    hipMemsetAsync(ctx, 0, (size_t)4096 * 64 * 4, stream);
    gemm_f16_v2<<<dim3(1, 8, 32), 256, 0, stream>>>(
        attn_ptr, nullptr, vT, nullptr, nullptr, ctx,
        64, 1024, 1024, 64,
        (long)1048576, (long)65536, (long)65536,
        /*c_half=*/0, /*atomic=*/1, /*nks=*/8, /*kchunk=*/128);

    // out = ctx @ Wo + bo (K=64: single iteration)
    gemm_f16_v2<<<dim3(8, 32, 1), 256, 0, stream>>>(
        ctx, nullptr, WoT, bo, nullptr, out_ptr,
        1024, 64, 64, 1024,
        0, 0, 0,
        /*c_half=*/0, /*atomic=*/0, /*nks=*/1, /*kchunk=*/64);
}

// Round 13
// 272.920 us; speedup vs baseline: 1.3097x; 1.0912x over previous
//
#include <hip/hip_runtime.h>
#include <hip/hip_bf16.h>
#include <stdint.h>

typedef _Float16 half8 __attribute__((ext_vector_type(8)));
typedef _Float16 half4 __attribute__((ext_vector_type(4)));
typedef float    f32x4 __attribute__((ext_vector_type(4)));

#define MFMA16(a, b, c) __builtin_amdgcn_mfma_f32_16x16x32_f16(a, b, c, 0, 0, 0)

// ---------------------------------------------------------------------------
// Generic fp32->fp16 transpose: X [R][C] fp32 -> Y [C][R] fp16, z-batched.
// ---------------------------------------------------------------------------
__global__ __launch_bounds__(256) void transpose_to_f16(
    const float* __restrict__ X, _Float16* __restrict__ Y,
    int R, int C, long inBS, long outBS)
{
    __shared__ float t[32][33];
    const int bz = blockIdx.z;
    X += (long)bz * inBS;
    Y += (long)bz * outBS;
    const int c0 = blockIdx.x * 32, r0 = blockIdx.y * 32;
    const int tx = threadIdx.x & 31, ty = threadIdx.x >> 5;
#pragma unroll
    for (int i = 0; i < 4; ++i)
        t[ty + i * 8][tx] = X[(long)(r0 + ty + i * 8) * C + c0 + tx];
    __syncthreads();
#pragma unroll
    for (int i = 0; i < 4; ++i)
        Y[(long)(c0 + ty + i * 8) * R + r0 + tx] = (_Float16)t[tx][ty + i * 8];
}

// ---------------------------------------------------------------------------
// MFMA GEMM v2 (unchanged from R9-R12 passing). C = A(fp32) @ BT(fp16).
// ---------------------------------------------------------------------------
__global__ __launch_bounds__(256, 2) void gemm_f16_v2(
    const float* __restrict__ A0, const float* __restrict__ A1,
    const _Float16* __restrict__ BT,
    const float* __restrict__ bias0, const float* __restrict__ bias1,
    void* __restrict__ Cout,
    int N, int lda, int ldbt, int ldc,
    long aBS, long bBS, long cBS,
    int c_half, int atomic, int nks, int kchunk)
{
    __shared__ __align__(16) _Float16 As[128][72];
    __shared__ __align__(16) _Float16 Bs[128][72];

    const int nt = blockIdx.x, mt = blockIdx.y;
    const int b = blockIdx.z / nks, ks = blockIdx.z % nks;
    const int kbeg = ks * kchunk;

    const float* A = A1 ? (b ? A1 : A0) : (A0 + (long)b * aBS);
    const _Float16* Bb = BT + (long)b * bBS;

    const int n0 = nt * 128;
    const int m0 = mt * 128;
    const int tid  = threadIdx.x;
    const int wave = tid >> 6, lane = tid & 63;
    const int m16  = lane & 15, quad = lane >> 4;

    f32x4 acc[2][8];
    {
        f32x4 z = {0.f, 0.f, 0.f, 0.f};
#pragma unroll
        for (int i = 0; i < 2; ++i)
#pragma unroll
            for (int j = 0; j < 8; ++j) acc[i][j] = z;
    }

    for (int k0 = kbeg; k0 < kbeg + kchunk; k0 += 64) {
        {
            const int cc = (tid & 15) * 4;
            const int rb = tid >> 4;
            float4 av[8];
#pragma unroll
            for (int p = 0; p < 8; ++p)
                av[p] = *(const float4*)(A + (long)(m0 + rb + p * 16) * lda + k0 + cc);
#pragma unroll
            for (int p = 0; p < 8; ++p) {
                half4 hv;
                hv[0] = (_Float16)av[p].x; hv[1] = (_Float16)av[p].y;
                hv[2] = (_Float16)av[p].z; hv[3] = (_Float16)av[p].w;
                *(half4*)&As[rb + p * 16][cc] = hv;
            }
        }
        {
            const int j  = tid >> 1;
            const int cc = (tid & 1) * 32;
            int jn = n0 + j; if (jn > N - 1) jn = N - 1;
            const _Float16* bp = Bb + (long)jn * ldbt + k0 + cc;
            half8 b0 = *(const half8*)(bp);
            half8 b1 = *(const half8*)(bp + 8);
            half8 b2 = *(const half8*)(bp + 16);
            half8 b3 = *(const half8*)(bp + 24);
            *(half8*)&Bs[j][cc]      = b0;
            *(half8*)&Bs[j][cc + 8]  = b1;
            *(half8*)&Bs[j][cc + 16] = b2;
            *(half8*)&Bs[j][cc + 24] = b3;
        }
        __syncthreads();
#pragma unroll
        for (int kss = 0; kss < 2; ++kss) {
            const int ko = kss * 32 + quad * 8;
            const half8 a0 = *(const half8*)&As[wave * 32 + m16][ko];
            const half8 a1 = *(const half8*)&As[wave * 32 + 16 + m16][ko];
#pragma unroll
            for (int c = 0; c < 8; ++c) {
                const half8 bf = *(const half8*)&Bs[c * 16 + m16][ko];
                acc[0][c] = MFMA16(a0, bf, acc[0][c]);
                acc[1][c] = MFMA16(a1, bf, acc[1][c]);
            }
        }
        __syncthreads();
    }

    const float* bias = b ? bias1 : bias0;
    const int addb = (bias != nullptr) && (kbeg == 0);
#pragma unroll
    for (int hh = 0; hh < 2; ++hh) {
#pragma unroll
        for (int c = 0; c < 8; ++c) {
            const int col = n0 + c * 16 + m16;
            if (col >= N) continue;
            const float bb = addb ? bias[col] : 0.f;
#pragma unroll
            for (int r = 0; r < 4; ++r) {
                const int row = m0 + wave * 32 + hh * 16 + quad * 4 + r;
                const float v = acc[hh][c][r] + bb;
                const long idx = (long)b * cBS + (long)row * ldc + col;
                if (atomic)      atomicAdd(&((float*)Cout)[idx], v);
                else if (c_half) ((_Float16*)Cout)[idx] = (_Float16)v;
                else             ((float*)Cout)[idx] = v;
            }
        }
    }
}

// ---------------------------------------------------------------------------
// Pass 1 v3: per (b,h,s) row stats — LDS-STAGED (the R12 pmean fix ported).
// R12 evidence: stats had the same scattered-read defect (FETCH 2x unique,
// 490 GB/s, MfmaUtil 2.6%, 4x redundant per-wave k loads). Now: stage the
// 64x64 q-tile (head slice) once, then loop k in 64x64 LDS tiles with
// coalesced batched loads (issued before the barrier -> latency overlaps
// previous tile's compute); all 4 waves share each tile via conflict-free
// ds_read_b128 (stride 72 halves = 2-way, free). Only the diagonal tile
// takes the causal predicate.
// ---------------------------------------------------------------------------
__global__ __launch_bounds__(256, 2) void attn_stats(
    const _Float16* __restrict__ q_all, const _Float16* __restrict__ k_all,
    float* __restrict__ m_out, float* __restrict__ il_out)
{
    const int st = blockIdx.x, h = blockIdx.y, b = blockIdx.z;
    const int tid = threadIdx.x, wave = tid >> 6, lane = tid & 63;
    const int m16 = lane & 15, quad = lane >> 4;
    const int s0 = st * 64;
    const int sw = s0 + wave * 16;

    __shared__ __align__(16) _Float16 qs[64][72];
    __shared__ __align__(16) _Float16 ks[64][72];

    // staging role: thread -> (row, 32B chunk)
    const int srow = tid >> 2;              // 0..63
    const int scol = (tid & 3) * 16;        // halves: 0,16,32,48

    // stage q-tile (rows s0.., cols h*64..) once
    {
        const _Float16* qsrc = q_all + ((long)(b * 1024 + s0 + srow)) * 1024 + h * 64 + scol;
        *(half8*)&qs[srow][scol]     = *(const half8*)(qsrc);
        *(half8*)&qs[srow][scol + 8] = *(const half8*)(qsrc + 8);
    }

    const _Float16* ksrcb = k_all + ((long)(b * 1024 + srow)) * 1024 + h * 64 + scol;

    float mr[4], lr[4];
#pragma unroll
    for (int r = 0; r < 4; ++r) { mr[r] = -3.0e38f; lr[r] = 0.f; }

    half8 a0, a1;
    for (int tt = 0; tt <= st; ++tt) {
        // issue k-tile loads (latency overlaps previous tile's compute)
        const _Float16* ksrc = ksrcb + (long)(tt * 64) * 1024;
        const half8 k0 = *(const half8*)(ksrc);
        const half8 k1 = *(const half8*)(ksrc + 8);

        __syncthreads();   // waves done reading prior ks (and, at tt=0, qs written)
        *(half8*)&ks[srow][scol]     = k0;
        *(half8*)&ks[srow][scol + 8] = k1;
        __syncthreads();   // tile visible

        if (tt == 0) {
            a0 = *(const half8*)&qs[wave * 16 + m16][quad * 8];
            a1 = *(const half8*)&qs[wave * 16 + m16][quad * 8 + 32];
        }

        if (tt < st) {
#pragma unroll
            for (int c = 0; c < 4; ++c) {
                const half8 b0 = *(const half8*)&ks[c * 16 + m16][quad * 8];
                const half8 b1 = *(const half8*)&ks[c * 16 + m16][quad * 8 + 32];
                f32x4 cc = {0.f, 0.f, 0.f, 0.f};
                cc = MFMA16(a0, b0, cc);
                cc = MFMA16(a1, b1, cc);
#pragma unroll
                for (int r = 0; r < 4; ++r) {
                    const float z  = cc[r] * 0.125f;
                    const float nm = fmaxf(mr[r], z);
                    lr[r] = lr[r] * __expf(mr[r] - nm) + __expf(z - nm);
                    mr[r] = nm;
                }
            }
        } else {
#pragma unroll
            for (int c = 0; c < 4; ++c) {
                const half8 b0 = *(const half8*)&ks[c * 16 + m16][quad * 8];
                const half8 b1 = *(const half8*)&ks[c * 16 + m16][quad * 8 + 32];
                f32x4 cc = {0.f, 0.f, 0.f, 0.f};
                cc = MFMA16(a0, b0, cc);
                cc = MFMA16(a1, b1, cc);
                const int col = tt * 64 + c * 16 + m16;
#pragma unroll
                for (int r = 0; r < 4; ++r) {
                    const int row = sw + quad * 4 + r;
                    if (col <= row) {
                        const float z  = cc[r] * 0.125f;
                        const float nm = fmaxf(mr[r], z);
                        lr[r] = lr[r] * __expf(mr[r] - nm) + __expf(z - nm);
                        mr[r] = nm;
                    }
                }
            }
        }
    }

    // merge across the 16 lanes sharing each row (same quad)
#pragma unroll
    for (int mk = 1; mk < 16; mk <<= 1) {
#pragma unroll
        for (int r = 0; r < 4; ++r) {
            const float om = __shfl_xor(mr[r], mk);
            const float ol = __shfl_xor(lr[r], mk);
            const float nm = fmaxf(mr[r], om);
            lr[r] = lr[r] * __expf(mr[r] - nm) + ol * __expf(om - nm);
            mr[r] = nm;
        }
    }
    if (m16 == 0) {
#pragma unroll
        for (int r = 0; r < 4; ++r) {
            const long idx = ((long)(b * 16 + h)) * 1024 + sw + quad * 4 + r;
            m_out[idx]  = mr[r];
            il_out[idx] = 1.f / lr[r];
        }
    }
}

// ---------------------------------------------------------------------------
// Pass 2 v4: attn_mean = (1/H) sum_h softmax — LDS-staged (R12-passing,
// unchanged).
// ---------------------------------------------------------------------------
__global__ __launch_bounds__(256, 2) void attn_pmean(
    const _Float16* __restrict__ q_all, const _Float16* __restrict__ k_all,
    const float* __restrict__ m_in, const float* __restrict__ il_in,
    float* __restrict__ attn)
{
    const int ttile = blockIdx.x, stile = blockIdx.y, b = blockIdx.z;
    const int tid = threadIdx.x;
    if (ttile > stile) {
        const int c4 = (tid & 15) * 4;
        float4 z = {0.f, 0.f, 0.f, 0.f};
#pragma unroll
        for (int i = 0; i < 4; ++i) {
            const int r = stile * 64 + (tid >> 4) + i * 16;
            *(float4*)&attn[((long)(b * 1024 + r)) * 1024 + ttile * 64 + c4] = z;
        }
        return;
    }

    __shared__ __align__(16) _Float16 qs[64][72];
    __shared__ __align__(16) _Float16 ks[64][72];

    const int wave = tid >> 6, lane = tid & 63;
    const int m16 = lane & 15, quad = lane >> 4;
    const int s0 = stile * 64;
    const int t0 = ttile * 64;
    const int sw = s0 + wave * 16;
    const int diag = (ttile == stile);

    const int srow = tid >> 2;
    const int scol = (tid & 3) * 16;

    const _Float16* qsrc = q_all + ((long)(b * 1024 + s0 + srow)) * 1024 + scol;
    const _Float16* ksrc = k_all + ((long)(b * 1024 + t0 + srow)) * 1024 + scol;
    const long sbase = ((long)(b * 16)) * 1024 + sw + quad * 4;

    float pm[4][4];
#pragma unroll
    for (int c = 0; c < 4; ++c)
#pragma unroll
        for (int r = 0; r < 4; ++r) pm[c][r] = 0.f;

    for (int h = 0; h < 16; ++h) {
        const int ho = h * 64;
        const half8 q0 = *(const half8*)(qsrc + ho);
        const half8 q1 = *(const half8*)(qsrc + ho + 8);
        const half8 k0 = *(const half8*)(ksrc + ho);
        const half8 k1 = *(const half8*)(ksrc + ho + 8);
        const long idx = sbase + (long)h * 1024;
        const float4 mv = *(const float4*)&m_in[idx];
        const float4 iv = *(const float4*)&il_in[idx];

        __syncthreads();
        *(half8*)&qs[srow][scol]     = q0;
        *(half8*)&qs[srow][scol + 8] = q1;
        *(half8*)&ks[srow][scol]     = k0;
        *(half8*)&ks[srow][scol + 8] = k1;
        __syncthreads();

        const half8 a0 = *(const half8*)&qs[wave * 16 + m16][quad * 8];
        const half8 a1 = *(const half8*)&qs[wave * 16 + m16][quad * 8 + 32];
        const float mrow[4] = {mv.x, mv.y, mv.z, mv.w};
        const float irow[4] = {iv.x, iv.y, iv.z, iv.w};

        if (!diag) {
#pragma unroll
            for (int c = 0; c < 4; ++c) {
                const half8 b0 = *(const half8*)&ks[c * 16 + m16][quad * 8];
                const half8 b1 = *(const half8*)&ks[c * 16 + m16][quad * 8 + 32];
                f32x4 cc = {0.f, 0.f, 0.f, 0.f};
                cc = MFMA16(a0, b0, cc);
                cc = MFMA16(a1, b1, cc);
#pragma unroll
                for (int r = 0; r < 4; ++r)
                    pm[c][r] += __expf(cc[r] * 0.125f - mrow[r]) * irow[r];
            }
        } else {
#pragma unroll
            for (int c = 0; c < 4; ++c) {
                const half8 b0 = *(const half8*)&ks[c * 16 + m16][quad * 8];
                const half8 b1 = *(const half8*)&ks[c * 16 + m16][quad * 8 + 32];
                f32x4 cc = {0.f, 0.f, 0.f, 0.f};
                cc = MFMA16(a0, b0, cc);
                cc = MFMA16(a1, b1, cc);
                const int col = t0 + c * 16 + m16;
#pragma unroll
                for (int r = 0; r < 4; ++r) {
                    const int row = sw + quad * 4 + r;
                    if (col <= row)
                        pm[c][r] += __expf(cc[r] * 0.125f - mrow[r]) * irow[r];
                }
            }
        }
    }

#pragma unroll
    for (int c = 0; c < 4; ++c) {
#pragma unroll
        for (int r = 0; r < 4; ++r) {
            const int row = sw + quad * 4 + r;
            const int col = t0 + c * 16 + m16;
            attn[((long)(b * 1024 + row)) * 1024 + col] = pm[c][r] * 0.0625f;
        }
    }
}

// ---------------------------------------------------------------------------
extern "C" void kernel_launch(void* const* d_in, const int* in_sizes, int n_in,
                              void* d_out, int out_size, void* d_ws, size_t ws_size,
                              hipStream_t stream)
{
    const float* queries = (const float*)d_in[0];
    const float* keys    = (const float*)d_in[1];
    const float* values  = (const float*)d_in[2];
    const float* Wq = (const float*)d_in[4];
    const float* bq = (const float*)d_in[5];
    const float* Wk = (const float*)d_in[6];
    const float* bk = (const float*)d_in[7];
    const float* Wv = (const float*)d_in[8];
    const float* bv = (const float*)d_in[9];
    const float* Wo = (const float*)d_in[10];
    const float* bo = (const float*)d_in[11];

    float* out_ptr  = (float*)d_out;                   // [4096][1024]
    float* attn_ptr = out_ptr + (long)4096 * 1024;     // [4][1024][1024]

    uint8_t* w = (uint8_t*)d_ws;
    size_t off = 0;
    auto alloc = [&](size_t bytes) {
        void* p = w + off;
        off = (off + bytes + 255) & ~(size_t)255;
        return p;
    };
    _Float16* WqkT  = (_Float16*)alloc((size_t)2 * 1024 * 1024 * 2); // WqT|WkT [n][d]
    _Float16* WvT   = (_Float16*)alloc((size_t)64 * 1024 * 2);       // [e][d]
    _Float16* WoT   = (_Float16*)alloc((size_t)1024 * 64 * 2);       // [d][e]
    _Float16* qkall = (_Float16*)alloc((size_t)2 * 4194304 * 2);     // qall|kall
    float*    vbuf  = (float*)alloc((size_t)4096 * 64 * 4);
    _Float16* vT    = (_Float16*)alloc((size_t)4 * 64 * 1024 * 2);   // per-b [e][t]
    float*    ctx   = (float*)alloc((size_t)4096 * 64 * 4);
    float*    mbuf  = (float*)alloc((size_t)65536 * 4);
    float*    ilbuf = (float*)alloc((size_t)65536 * 4);
    (void)ws_size; (void)in_sizes; (void)n_in; (void)out_size;

    _Float16* qall = qkall;
    _Float16* kall = qkall + (long)4194304;

    // weight transposes/conversions
    transpose_to_f16<<<dim3(2, 32, 16), 256, 0, stream>>>(Wq, WqkT, 1024, 64, 65536, 65536);
    transpose_to_f16<<<dim3(2, 32, 16), 256, 0, stream>>>(Wk, WqkT + (long)1024 * 1024, 1024, 64, 65536, 65536);
    transpose_to_f16<<<dim3(2, 32, 1),  256, 0, stream>>>(Wv, WvT, 1024, 64, 0, 0);
    transpose_to_f16<<<dim3(32, 2, 1),  256, 0, stream>>>(Wo, WoT, 64, 1024, 0, 0);

    // fused q+k projection: z selects queries/Wq/bq vs keys/Wk/bk; 512 blocks
    gemm_f16_v2<<<dim3(8, 32, 2), 256, 0, stream>>>(
        queries, keys, WqkT, bq, bk, qkall,
        1024, 1024, 1024, 1024,
        0, (long)1048576, (long)4194304,
        /*c_half=*/1, /*atomic=*/0, /*nks=*/1, /*kchunk=*/1024);

    // v projection: split-K x8 atomic into vbuf (zeroed) -> 256 blocks
    hipMemsetAsync(vbuf, 0, (size_t)4096 * 64 * 4, stream);
    gemm_f16_v2<<<dim3(1, 32, 8), 256, 0, stream>>>(
        values, nullptr, WvT, bv, nullptr, vbuf,
        64, 1024, 1024, 64,
        0, 0, 0,
        /*c_half=*/0, /*atomic=*/1, /*nks=*/8, /*kchunk=*/128);

    // vT per batch: [1024][64] -> [64][1024] fp16
    transpose_to_f16<<<dim3(2, 32, 4), 256, 0, stream>>>(vbuf, vT, 1024, 64, 65536, 65536);

    // softmax stats then LDS-staged head-averaged probabilities
    attn_stats<<<dim3(16, 16, 4), 256, 0, stream>>>(qall, kall, mbuf, ilbuf);
    attn_pmean<<<dim3(16, 16, 4), 256, 0, stream>>>(qall, kall, mbuf, ilbuf, attn_ptr);

    // ctx[b] = attn_mean[b] @ v[b]: batch x split-K x8 atomic -> 256 blocks
    hipMemsetAsync(ctx, 0, (size_t)4096 * 64 * 4, stream);
    gemm_f16_v2<<<dim3(1, 8, 32), 256, 0, stream>>>(
        attn_ptr, nullptr, vT, nullptr, nullptr, ctx,
        64, 1024, 1024, 64,
        (long)1048576, (long)65536, (long)65536,
        /*c_half=*/0, /*atomic=*/1, /*nks=*/8, /*kchunk=*/128);

    // out = ctx @ Wo + bo (K=64: single iteration)
    gemm_f16_v2<<<dim3(8, 32, 1), 256, 0, stream>>>(
        ctx, nullptr, WoT, bo, nullptr, out_ptr,
        1024, 64, 64, 1024,
        0, 0, 0,
        /*c_half=*/0, /*atomic=*/0, /*nks=*/1, /*kchunk=*/64);
}